// Round 1
// baseline (3833.325 us; speedup 1.0000x reference)
//
#include <hip/hip_runtime.h>

#define E_NUM 16
#define DM 2048
#define DH 1408
#define NTOK 32768
#define BM 128
#define BN 128
#define BK 64
#define TMAX 272   // sum_e ceil(c_e/128) <= 256 + 16

typedef unsigned short u16;
typedef unsigned int u32;
typedef float f32x4 __attribute__((ext_vector_type(4)));
typedef __bf16 bf16x8 __attribute__((ext_vector_type(8)));
typedef short short8 __attribute__((ext_vector_type(8)));

__device__ __forceinline__ u16 f2bf(float x) {
  u32 u = __builtin_bit_cast(u32, x);
  u = (u + 0x7FFFu + ((u >> 16) & 1u)) >> 16;   // RNE
  return (u16)u;
}
__device__ __forceinline__ u32 f2bf2(float lo, float hi) {
  return (u32)f2bf(lo) | ((u32)f2bf(hi) << 16);
}

// SFINAE shim: gfx950 bf16 MFMA builtin signature is <8 x bfloat> upstream,
// but some toolchains use <8 x i16>. Pick whichever compiles.
template <typename V>
__device__ __forceinline__ auto mfma_16x16x32(V a, V b, f32x4 c, int)
    -> decltype(__builtin_amdgcn_mfma_f32_16x16x32_bf16(a, b, c, 0, 0, 0)) {
  return __builtin_amdgcn_mfma_f32_16x16x32_bf16(a, b, c, 0, 0, 0);
}
template <typename V>
__device__ __forceinline__ f32x4 mfma_16x16x32(V a, V b, f32x4 c, long) {
  return __builtin_amdgcn_mfma_f32_16x16x32_bf16(
      __builtin_bit_cast(short8, a), __builtin_bit_cast(short8, b), c, 0, 0, 0);
}
__device__ __forceinline__ f32x4 MFMA(bf16x8 a, bf16x8 b, f32x4 c) {
  return mfma_16x16x32(a, b, c, 0);
}

// Transpose + convert: src f32 [E][K][N] -> dst bf16 [E][N][K]
__global__ void tcvt(const float* __restrict__ src, u16* __restrict__ dst,
                     int K, int N) {
  __shared__ float t[32][33];
  const int e = blockIdx.z;
  const size_t base = (size_t)e * K * N;
  const int k0 = blockIdx.x * 32, n0 = blockIdx.y * 32;
  const int tx = threadIdx.x & 31, ty = threadIdx.x >> 5;  // ty 0..7
#pragma unroll
  for (int i = 0; i < 4; i++)
    t[ty + 8 * i][tx] = src[base + (size_t)(k0 + ty + 8 * i) * N + (n0 + tx)];
  __syncthreads();
#pragma unroll
  for (int i = 0; i < 4; i++) {
    int n = ty + 8 * i;
    dst[base + (size_t)(n0 + n) * K + (k0 + tx)] = f2bf(t[tx][n]);
  }
}

// Map linear row-tile index -> (expert, row0, valid). Returns false past end.
__device__ __forceinline__ bool tile_map(const int* __restrict__ cnt, int t,
                                         int& e_out, int& row0, int& valid) {
  int e = -1, ti = 0, seg0 = 0, segc = 0, tacc = 0, off = 0;
#pragma unroll
  for (int i = 0; i < E_NUM; i++) {
    int ci = cnt[i];
    int nt = (ci + BM - 1) >> 7;
    if (e < 0 && t < tacc + nt) { e = i; ti = t - tacc; seg0 = off; segc = ci; }
    tacc += nt; off += ci;
  }
  if (e < 0) return false;
  e_out = e;
  row0 = seg0 + ti * BM;
  int v = seg0 + segc - row0;
  valid = v < BM ? v : BM;
  return true;
}

// Fused gate+up grouped GEMM + SwiGLU. X f32 [NTOK][DM]; WgT/WuT bf16 [E][DH][DM];
// H bf16 [NTOK][DH].
__global__ __launch_bounds__(256, 2) void gemm_gate_up(
    const float* __restrict__ X, const u16* __restrict__ WgT,
    const u16* __restrict__ WuT, const int* __restrict__ cnt,
    u16* __restrict__ H) {
  __shared__ u16 As[BM * BK];
  __shared__ u16 Bgs[BN * BK];
  __shared__ u16 Bus[BN * BK];

  int e, row0, valid;
  if (!tile_map(cnt, blockIdx.x, e, row0, valid)) return;
  const int n0 = blockIdx.y * BN;

  const int tid = threadIdx.x;
  const int lane = tid & 63;
  const int wave = tid >> 6;
  const int wr = (wave >> 1) * 64;
  const int wc = (wave & 1) * 64;
  const int l15 = lane & 15, l4 = lane >> 4;

  // staging: unit uid = j*256+tid handles 8 elems; row=uid>>3, ks=(uid&7)*8
  u32 aoff[4], bgo[4], lso[4];
#pragma unroll
  for (int j = 0; j < 4; j++) {
    int uid = j * 256 + tid;
    int row = uid >> 3;
    int ks = (uid & 7) * 8;
    int r = row < valid ? row : 0;
    aoff[j] = (u32)(((size_t)(row0 + r) * DM + ks) * 4);          // bytes
    bgo[j] = (u32)((((size_t)e * DH + (n0 + row)) * DM + ks) * 2); // bytes
    lso[j] = (u32)(row * BK + ks);                                 // elems
  }

  f32x4 accg[4][4], accu[4][4];
#pragma unroll
  for (int i = 0; i < 4; i++)
#pragma unroll
    for (int j = 0; j < 4; j++) {
      accg[i][j] = (f32x4){0.f, 0.f, 0.f, 0.f};
      accu[i][j] = (f32x4){0.f, 0.f, 0.f, 0.f};
    }

  float4 av0[4], av1[4];
  uint4 bgv[4], buv[4];
  const int NK = DM / BK;  // 32

#pragma unroll
  for (int j = 0; j < 4; j++) {
    const char* ap = (const char*)X + aoff[j];
    av0[j] = *(const float4*)ap;
    av1[j] = *(const float4*)(ap + 16);
    bgv[j] = *(const uint4*)((const char*)WgT + bgo[j]);
    buv[j] = *(const uint4*)((const char*)WuT + bgo[j]);
  }
#pragma unroll
  for (int j = 0; j < 4; j++) {
    uint4 aw;
    aw.x = f2bf2(av0[j].x, av0[j].y); aw.y = f2bf2(av0[j].z, av0[j].w);
    aw.z = f2bf2(av1[j].x, av1[j].y); aw.w = f2bf2(av1[j].z, av1[j].w);
    *(uint4*)&As[lso[j]] = aw;
    *(uint4*)&Bgs[lso[j]] = bgv[j];
    *(uint4*)&Bus[lso[j]] = buv[j];
  }
  __syncthreads();

  for (int kt = 0; kt < NK; kt++) {
    if (kt + 1 < NK) {
#pragma unroll
      for (int j = 0; j < 4; j++) {
        const char* ap = (const char*)X + aoff[j] + (size_t)(kt + 1) * BK * 4;
        av0[j] = *(const float4*)ap;
        av1[j] = *(const float4*)(ap + 16);
        bgv[j] = *(const uint4*)((const char*)WgT + bgo[j] + (size_t)(kt + 1) * BK * 2);
        buv[j] = *(const uint4*)((const char*)WuT + bgo[j] + (size_t)(kt + 1) * BK * 2);
      }
    }
#pragma unroll
    for (int kh = 0; kh < 2; kh++) {
      bf16x8 af[4];
#pragma unroll
      for (int i = 0; i < 4; i++) {
        uint4 v = *(const uint4*)&As[(wr + i * 16 + l15) * BK + kh * 32 + l4 * 8];
        af[i] = __builtin_bit_cast(bf16x8, v);
      }
#pragma unroll
      for (int j = 0; j < 4; j++) {
        uint4 vg = *(const uint4*)&Bgs[(wc + j * 16 + l15) * BK + kh * 32 + l4 * 8];
        uint4 vu = *(const uint4*)&Bus[(wc + j * 16 + l15) * BK + kh * 32 + l4 * 8];
        bf16x8 bg = __builtin_bit_cast(bf16x8, vg);
        bf16x8 bu = __builtin_bit_cast(bf16x8, vu);
#pragma unroll
        for (int i = 0; i < 4; i++) {
          accg[i][j] = MFMA(af[i], bg, accg[i][j]);
          accu[i][j] = MFMA(af[i], bu, accu[i][j]);
        }
      }
    }
    __syncthreads();
    if (kt + 1 < NK) {
#pragma unroll
      for (int j = 0; j < 4; j++) {
        uint4 aw;
        aw.x = f2bf2(av0[j].x, av0[j].y); aw.y = f2bf2(av0[j].z, av0[j].w);
        aw.z = f2bf2(av1[j].x, av1[j].y); aw.w = f2bf2(av1[j].z, av1[j].w);
        *(uint4*)&As[lso[j]] = aw;
        *(uint4*)&Bgs[lso[j]] = bgv[j];
        *(uint4*)&Bus[lso[j]] = buv[j];
      }
      __syncthreads();
    }
  }

  // epilogue: h = silu(gate) * up, bf16
#pragma unroll
  for (int i = 0; i < 4; i++) {
#pragma unroll
    for (int j = 0; j < 4; j++) {
      f32x4 g = accg[i][j], u = accu[i][j];
#pragma unroll
      for (int r = 0; r < 4; r++) {
        int rl = wr + i * 16 + l4 * 4 + r;
        if (rl < valid) {
          float gv = g[r];
          float hv = gv / (1.f + __expf(-gv)) * u[r];
          H[(size_t)(row0 + rl) * DH + (n0 + wc + j * 16 + l15)] = f2bf(hv);
        }
      }
    }
  }
}

// Down grouped GEMM. Hm bf16 [NTOK][DH]; WdT bf16 [E][DM][DH]; Out f32 [NTOK][DM].
__global__ __launch_bounds__(256, 2) void gemm_down(
    const u16* __restrict__ Hm, const u16* __restrict__ WdT,
    const int* __restrict__ cnt, float* __restrict__ Out) {
  __shared__ u16 As[BM * BK];
  __shared__ u16 Bs[BN * BK];

  int e, row0, valid;
  if (!tile_map(cnt, blockIdx.x, e, row0, valid)) return;
  const int n0 = blockIdx.y * BN;

  const int tid = threadIdx.x;
  const int lane = tid & 63;
  const int wave = tid >> 6;
  const int wr = (wave >> 1) * 64;
  const int wc = (wave & 1) * 64;
  const int l15 = lane & 15, l4 = lane >> 4;

  u32 aoff[4], boff[4], lso[4];
#pragma unroll
  for (int j = 0; j < 4; j++) {
    int uid = j * 256 + tid;
    int row = uid >> 3;
    int ks = (uid & 7) * 8;
    int r = row < valid ? row : 0;
    aoff[j] = (u32)(((size_t)(row0 + r) * DH + ks) * 2);
    boff[j] = (u32)((((size_t)e * DM + (n0 + row)) * DH + ks) * 2);
    lso[j] = (u32)(row * BK + ks);
  }

  f32x4 acc[4][4];
#pragma unroll
  for (int i = 0; i < 4; i++)
#pragma unroll
    for (int j = 0; j < 4; j++) acc[i][j] = (f32x4){0.f, 0.f, 0.f, 0.f};

  uint4 avv[4], bvv[4];
  const int NK = DH / BK;  // 22

#pragma unroll
  for (int j = 0; j < 4; j++) {
    avv[j] = *(const uint4*)((const char*)Hm + aoff[j]);
    bvv[j] = *(const uint4*)((const char*)WdT + boff[j]);
  }
#pragma unroll
  for (int j = 0; j < 4; j++) {
    *(uint4*)&As[lso[j]] = avv[j];
    *(uint4*)&Bs[lso[j]] = bvv[j];
  }
  __syncthreads();

  for (int kt = 0; kt < NK; kt++) {
    if (kt + 1 < NK) {
#pragma unroll
      for (int j = 0; j < 4; j++) {
        avv[j] = *(const uint4*)((const char*)Hm + aoff[j] + (size_t)(kt + 1) * BK * 2);
        bvv[j] = *(const uint4*)((const char*)WdT + boff[j] + (size_t)(kt + 1) * BK * 2);
      }
    }
#pragma unroll
    for (int kh = 0; kh < 2; kh++) {
      bf16x8 af[4];
#pragma unroll
      for (int i = 0; i < 4; i++) {
        uint4 v = *(const uint4*)&As[(wr + i * 16 + l15) * BK + kh * 32 + l4 * 8];
        af[i] = __builtin_bit_cast(bf16x8, v);
      }
#pragma unroll
      for (int j = 0; j < 4; j++) {
        uint4 vb = *(const uint4*)&Bs[(wc + j * 16 + l15) * BK + kh * 32 + l4 * 8];
        bf16x8 bf = __builtin_bit_cast(bf16x8, vb);
#pragma unroll
        for (int i = 0; i < 4; i++) acc[i][j] = MFMA(af[i], bf, acc[i][j]);
      }
    }
    __syncthreads();
    if (kt + 1 < NK) {
#pragma unroll
      for (int j = 0; j < 4; j++) {
        *(uint4*)&As[lso[j]] = avv[j];
        *(uint4*)&Bs[lso[j]] = bvv[j];
      }
      __syncthreads();
    }
  }

#pragma unroll
  for (int i = 0; i < 4; i++) {
#pragma unroll
    for (int j = 0; j < 4; j++) {
#pragma unroll
      for (int r = 0; r < 4; r++) {
        int rl = wr + i * 16 + l4 * 4 + r;
        if (rl < valid)
          Out[(size_t)(row0 + rl) * DM + (n0 + wc + j * 16 + l15)] = acc[i][j][r];
      }
    }
  }
}

extern "C" void kernel_launch(void* const* d_in, const int* in_sizes, int n_in,
                              void* d_out, int out_size, void* d_ws, size_t ws_size,
                              hipStream_t stream) {
  const float* inp = (const float*)d_in[0];
  const float* w_gate = (const float*)d_in[1];
  const float* w_up = (const float*)d_in[2];
  const float* w_down = (const float*)d_in[3];
  const int* cnt = (const int*)d_in[4];
  float* out = (float*)d_out;

  const size_t WELEMS = (size_t)E_NUM * DM * DH;  // 46,137,344 (== NTOK*DH)
  if (ws_size < 3 * WELEMS * sizeof(u16)) return;  // 277 MB needed

  u16* wgT = (u16*)d_ws;       // [E][DH][DM]
  u16* wuT = wgT + WELEMS;     // [E][DH][DM]
  u16* H = wuT + WELEMS;       // [NTOK][DH]

  dim3 blk(256);
  tcvt<<<dim3(DM / 32, DH / 32, E_NUM), blk, 0, stream>>>(w_gate, wgT, DM, DH);
  tcvt<<<dim3(DM / 32, DH / 32, E_NUM), blk, 0, stream>>>(w_up, wuT, DM, DH);
  gemm_gate_up<<<dim3(TMAX, DH / BN), blk, 0, stream>>>(inp, wgT, wuT, cnt, H);
  // w_gate^T region is dead now; reuse it for w_down^T (stream-serialized).
  tcvt<<<dim3(DH / 32, DM / 32, E_NUM), blk, 0, stream>>>(w_down, wgT, DH, DM);
  gemm_down<<<dim3(TMAX, DM / BN), blk, 0, stream>>>(H, wgT, cnt, out);
}

// Round 2
// 1167.933 us; speedup vs baseline: 3.2821x; 3.2821x over previous
//
#include <hip/hip_runtime.h>

#define E_NUM 16
#define DM 2048
#define DH 1408
#define NTOK 32768
#define TMAX 272          // sum_e ceil(c_e/128) <= 256 + 16
#define TILE_U16 8192     // 128 rows x 64 cols bf16 tile image
#define HT_ROWSTRIDE (22 * TILE_U16)   // u16 per 128-token row-tile of H

typedef unsigned short u16;
typedef unsigned int u32;
typedef float f32x4 __attribute__((ext_vector_type(4)));
typedef __bf16 bf16x8 __attribute__((ext_vector_type(8)));
typedef short short8 __attribute__((ext_vector_type(8)));

__device__ __forceinline__ u16 f2bf(float x) {
  u32 u = __builtin_bit_cast(u32, x);
  u = (u + 0x7FFFu + ((u >> 16) & 1u)) >> 16;   // RNE
  return (u16)u;
}
__device__ __forceinline__ u32 f2bf2(float lo, float hi) {
  return (u32)f2bf(lo) | ((u32)f2bf(hi) << 16);
}

// MFMA shim (signature-agnostic), proven in R1.
template <typename V>
__device__ __forceinline__ auto mfma_16x16x32(V a, V b, f32x4 c, int)
    -> decltype(__builtin_amdgcn_mfma_f32_16x16x32_bf16(a, b, c, 0, 0, 0)) {
  return __builtin_amdgcn_mfma_f32_16x16x32_bf16(a, b, c, 0, 0, 0);
}
template <typename V>
__device__ __forceinline__ f32x4 mfma_16x16x32(V a, V b, f32x4 c, long) {
  return __builtin_amdgcn_mfma_f32_16x16x32_bf16(
      __builtin_bit_cast(short8, a), __builtin_bit_cast(short8, b), c, 0, 0, 0);
}
__device__ __forceinline__ f32x4 MFMA(bf16x8 a, bf16x8 b, f32x4 c) {
  return mfma_16x16x32(a, b, c, 0);
}

__device__ __forceinline__ void gll16(const void* g, void* l) {
  __builtin_amdgcn_global_load_lds((const u32*)g, (u32*)l, 16, 0, 0);
}

__device__ __forceinline__ bf16x8 ld_frag(const u16* p) {
  return __builtin_bit_cast(bf16x8, *(const uint4*)p);
}

// ---------------------------------------------------------------------------
// Weight tiler: src f32 [E][K][N] -> dst bf16 tile images
// [E][N/128][K/64][8192], image pos (row, c) holds W[k0+(c^(row&7))*8+j][n0+row]
// grid (K/64, N/128, E), 256 threads
// ---------------------------------------------------------------------------
__global__ void wtile(const float* __restrict__ src, u16* __restrict__ dst,
                      int K, int N) {
  __shared__ float t[64][133];     // +5 pad: conflict-light gather
  __shared__ u16 img[TILE_U16];
  const int kt = blockIdx.x, nt = blockIdx.y, e = blockIdx.z;
  const int tid = threadIdx.x;
  const size_t sbase = (size_t)e * K * N + (size_t)kt * 64 * N + (size_t)nt * 128;

#pragma unroll
  for (int i = 0; i < 8; i++) {              // 2048 float4 units
    int uid = i * 256 + tid;
    int kr = uid >> 5, nc = (uid & 31) * 4;
    float4 v = *(const float4*)&src[sbase + (size_t)kr * N + nc];
    t[kr][nc + 0] = v.x; t[kr][nc + 1] = v.y;
    t[kr][nc + 2] = v.z; t[kr][nc + 3] = v.w;
  }
  __syncthreads();
#pragma unroll
  for (int i = 0; i < 4; i++) {              // 1024 image chunks
    int uid = i * 256 + tid;
    int row = uid >> 3, c = uid & 7;
    int kc = (c ^ (row & 7)) * 8;
    uint4 w;
    w.x = f2bf2(t[kc + 0][row], t[kc + 1][row]);
    w.y = f2bf2(t[kc + 2][row], t[kc + 3][row]);
    w.z = f2bf2(t[kc + 4][row], t[kc + 5][row]);
    w.w = f2bf2(t[kc + 6][row], t[kc + 7][row]);
    *(uint4*)&img[uid * 8] = w;
  }
  __syncthreads();
  const size_t dbase = (((size_t)e * (N / 128) + nt) * (K / 64) + kt) * TILE_U16;
#pragma unroll
  for (int i = 0; i < 4; i++) {
    int uid = i * 256 + tid;
    *(uint4*)&dst[dbase + uid * 8] = *(const uint4*)&img[uid * 8];
  }
}

// Map linear row-tile index -> (expert, row0, valid).
__device__ __forceinline__ bool tile_map(const int* __restrict__ cnt, int t,
                                         int& e_out, int& row0, int& valid) {
  int e = -1, ti = 0, seg0 = 0, segc = 0, tacc = 0, off = 0;
#pragma unroll
  for (int i = 0; i < E_NUM; i++) {
    int ci = cnt[i];
    int nt = (ci + 127) >> 7;
    if (e < 0 && t < tacc + nt) { e = i; ti = t - tacc; seg0 = off; segc = ci; }
    tacc += nt; off += ci;
  }
  if (e < 0) return false;
  e_out = e;
  row0 = seg0 + ti * 128;
  int v = seg0 + segc - row0;
  valid = v < 128 ? v : 128;
  return true;
}

// ---------------------------------------------------------------------------
// Fused gate+up grouped GEMM + SwiGLU.
// X f32 [NTOK][DM]; WgT/WuT tiled bf16 [E][11][32][8192]; H tiled bf16 images.
// ---------------------------------------------------------------------------
__global__ __launch_bounds__(256, 2) void gemm_gate_up(
    const float* __restrict__ X, const u16* __restrict__ WgT,
    const u16* __restrict__ WuT, const int* __restrict__ cnt,
    u16* __restrict__ H) {
  __shared__ u16 As[TILE_U16], Bgs[TILE_U16], Bus[TILE_U16];

  int e, row0, valid;
  if (!tile_map(cnt, blockIdx.x, e, row0, valid)) return;
  const int n0t = blockIdx.y;  // 0..10

  const int tid = threadIdx.x;
  const int lane = tid & 63;
  const int wave = tid >> 6;
  const int wr = (wave >> 1) * 64, wc = (wave & 1) * 64;
  const int l15 = lane & 15, l4 = lane >> 4;

  // A staging geometry: unit u = q*256+tid -> lds row lr=u>>3, chunk c=u&7
  const float* pA[4];
  u32 aso[4];
#pragma unroll
  for (int q = 0; q < 4; q++) {
    int u = q * 256 + tid;
    int lr = u >> 3, c = u & 7;
    int R = row0 + (lr < valid ? lr : 0);
    pA[q] = X + (size_t)R * DM + c * 8;
    aso[q] = lr * 64 + ((c ^ (R & 7)) * 8);
  }
  const size_t btb = (((size_t)e * 11 + n0t) * 32) * TILE_U16;

  f32x4 accg[4][4], accu[4][4];
#pragma unroll
  for (int i = 0; i < 4; i++)
#pragma unroll
    for (int j = 0; j < 4; j++) {
      accg[i][j] = (f32x4){0.f, 0.f, 0.f, 0.f};
      accu[i][j] = (f32x4){0.f, 0.f, 0.f, 0.f};
    }

  float4 a0[4], a1[4];
#pragma unroll
  for (int q = 0; q < 4; q++) {
    a0[q] = *(const float4*)pA[q];
    a1[q] = *(const float4*)(pA[q] + 4);
  }

  for (int kt = 0; kt < 32; kt++) {
    // stage current tile: B via global_load_lds (pre-swizzled images), A via cvt+ds_write
    const u16* bgp = WgT + btb + (size_t)kt * TILE_U16;
    const u16* bup = WuT + btb + (size_t)kt * TILE_U16;
#pragma unroll
    for (int q = 0; q < 4; q++) {
      int u = q * 256 + tid;
      gll16(bgp + u * 8, &Bgs[u * 8]);
      gll16(bup + u * 8, &Bus[u * 8]);
    }
#pragma unroll
    for (int q = 0; q < 4; q++) {
      uint4 w;
      w.x = f2bf2(a0[q].x, a0[q].y); w.y = f2bf2(a0[q].z, a0[q].w);
      w.z = f2bf2(a1[q].x, a1[q].y); w.w = f2bf2(a1[q].z, a1[q].w);
      *(uint4*)&As[aso[q]] = w;
    }
    if (kt + 1 < 32) {  // prefetch next A into regs (latency hidden under MFMA)
#pragma unroll
      for (int q = 0; q < 4; q++) {
        const float* ap = pA[q] + (kt + 1) * 64;
        a0[q] = *(const float4*)ap;
        a1[q] = *(const float4*)(ap + 4);
      }
    }
    __syncthreads();   // drains gll + ds_write
#pragma unroll
    for (int kh = 0; kh < 2; kh++) {
      bf16x8 af[4];
#pragma unroll
      for (int i = 0; i < 4; i++) {
        int lr = wr + i * 16 + l15;
        int sw = ((kh * 4 + l4) ^ ((row0 + lr) & 7)) * 8;
        af[i] = ld_frag(&As[lr * 64 + sw]);
      }
#pragma unroll
      for (int j = 0; j < 4; j++) {
        int br = wc + j * 16 + l15;
        int boff = br * 64 + (((kh * 4 + l4) ^ (br & 7)) * 8);
        bf16x8 bg = ld_frag(&Bgs[boff]);
        bf16x8 bu = ld_frag(&Bus[boff]);
#pragma unroll
        for (int i = 0; i < 4; i++) {
          accg[i][j] = MFMA(af[i], bg, accg[i][j]);
          accu[i][j] = MFMA(af[i], bu, accu[i][j]);
        }
      }
    }
    __syncthreads();
  }

  // epilogue: h = silu(gate)*up -> H tiled-swizzled image
#pragma unroll
  for (int j = 0; j < 4; j++) {
    int col = n0t * 128 + wc + j * 16 + l15;
    int kt_h = col >> 6, cc = (col & 63) >> 3, ce = col & 7;
#pragma unroll
    for (int i = 0; i < 4; i++) {
      f32x4 g = accg[i][j], u = accu[i][j];
#pragma unroll
      for (int r = 0; r < 4; r++) {
        int rl = wr + i * 16 + l4 * 4 + r;
        if (rl < valid) {
          int R = row0 + rl;
          float gv = g[r];
          float hv = gv / (1.f + __expf(-gv)) * u[r];
          size_t idx = (size_t)(R >> 7) * HT_ROWSTRIDE + (size_t)kt_h * TILE_U16 +
                       (R & 127) * 64 + ((cc ^ (R & 7)) * 8) + ce;
          H[idx] = f2bf(hv);
        }
      }
    }
  }
}

// ---------------------------------------------------------------------------
// Down grouped GEMM: Ht tiled bf16 images; WdT tiled bf16 [E][16][22][8192];
// Out f32 [NTOK][DM]. Both operands staged via global_load_lds.
// ---------------------------------------------------------------------------
__global__ __launch_bounds__(256, 3) void gemm_down(
    const u16* __restrict__ Ht, const u16* __restrict__ WdT,
    const int* __restrict__ cnt, float* __restrict__ Out) {
  __shared__ u16 As[TILE_U16], Bs[TILE_U16];

  int e, row0, valid;
  if (!tile_map(cnt, blockIdx.x, e, row0, valid)) return;
  const int n0t = blockIdx.y;  // 0..15

  const int tid = threadIdx.x;
  const int lane = tid & 63;
  const int wave = tid >> 6;
  const int wr = (wave >> 1) * 64, wc = (wave & 1) * 64;
  const int l15 = lane & 15, l4 = lane >> 4;

  const u16* pA[4];
#pragma unroll
  for (int q = 0; q < 4; q++) {
    int u = q * 256 + tid;
    int lr = u >> 3, c = u & 7;
    int R = row0 + (lr < valid ? lr : 0);
    pA[q] = Ht + (size_t)(R >> 7) * HT_ROWSTRIDE + (size_t)(R & 127) * 64 + c * 8;
  }
  const size_t btb = (((size_t)e * 16 + n0t) * 22) * TILE_U16;

  f32x4 acc[4][4];
#pragma unroll
  for (int i = 0; i < 4; i++)
#pragma unroll
    for (int j = 0; j < 4; j++) acc[i][j] = (f32x4){0.f, 0.f, 0.f, 0.f};

  for (int kt = 0; kt < 22; kt++) {
    const u16* bp = WdT + btb + (size_t)kt * TILE_U16;
#pragma unroll
    for (int q = 0; q < 4; q++) {
      int u = q * 256 + tid;
      gll16(pA[q] + (size_t)kt * TILE_U16, &As[u * 8]);
      gll16(bp + u * 8, &Bs[u * 8]);
    }
    __syncthreads();
#pragma unroll
    for (int kh = 0; kh < 2; kh++) {
      bf16x8 af[4];
#pragma unroll
      for (int i = 0; i < 4; i++) {
        int lr = wr + i * 16 + l15;
        int sw = ((kh * 4 + l4) ^ ((row0 + lr) & 7)) * 8;
        af[i] = ld_frag(&As[lr * 64 + sw]);
      }
#pragma unroll
      for (int j = 0; j < 4; j++) {
        int br = wc + j * 16 + l15;
        int boff = br * 64 + (((kh * 4 + l4) ^ (br & 7)) * 8);
        bf16x8 bf = ld_frag(&Bs[boff]);
#pragma unroll
        for (int i = 0; i < 4; i++) acc[i][j] = MFMA(af[i], bf, acc[i][j]);
      }
    }
    __syncthreads();
  }

#pragma unroll
  for (int j = 0; j < 4; j++) {
#pragma unroll
    for (int i = 0; i < 4; i++) {
#pragma unroll
      for (int r = 0; r < 4; r++) {
        int rl = wr + i * 16 + l4 * 4 + r;
        if (rl < valid)
          Out[(size_t)(row0 + rl) * DM + n0t * 128 + wc + j * 16 + l15] =
              acc[i][j][r];
      }
    }
  }
}

extern "C" void kernel_launch(void* const* d_in, const int* in_sizes, int n_in,
                              void* d_out, int out_size, void* d_ws, size_t ws_size,
                              hipStream_t stream) {
  const float* inp = (const float*)d_in[0];
  const float* w_gate = (const float*)d_in[1];
  const float* w_up = (const float*)d_in[2];
  const float* w_down = (const float*)d_in[3];
  const int* cnt = (const int*)d_in[4];
  float* out = (float*)d_out;

  const size_t WELEMS = (size_t)E_NUM * DM * DH;  // 46,137,344 u16 each
  if (ws_size < 3 * WELEMS * sizeof(u16)) return;

  u16* wgT = (u16*)d_ws;      // gate tiles [E][11][32][8192]; later w_down tiles
  u16* wuT = wgT + WELEMS;    // up tiles
  u16* Ht = wuT + WELEMS;     // H tile images [256][22][8192]

  dim3 blk(256);
  wtile<<<dim3(DM / 64, DH / 128, E_NUM), blk, 0, stream>>>(w_gate, wgT, DM, DH);
  wtile<<<dim3(DM / 64, DH / 128, E_NUM), blk, 0, stream>>>(w_up, wuT, DM, DH);
  gemm_gate_up<<<dim3(TMAX, DH / 128), blk, 0, stream>>>(inp, wgT, wuT, cnt, Ht);
  // wgT region dead now; reuse for w_down tiles [E][16][22][8192]
  wtile<<<dim3(DH / 64, DM / 128, E_NUM), blk, 0, stream>>>(w_down, wgT, DH, DM);
  gemm_down<<<dim3(TMAX, DM / 128), blk, 0, stream>>>(Ht, wgT, cnt, out);
}